// Round 1
// baseline (982.596 us; speedup 1.0000x reference)
//
#include <hip/hip_runtime.h>
#include <hip/hip_bf16.h>
#include <math.h>

// ---------------- degree / CSR build ----------------

__global__ __launch_bounds__(256) void count_kernel(const int* __restrict__ dst, int* __restrict__ cnt, int E) {
    for (int e = blockIdx.x * blockDim.x + threadIdx.x; e < E; e += gridDim.x * blockDim.x)
        atomicAdd(&cnt[dst[e]], 1);
}

__global__ __launch_bounds__(256) void dinv_kernel(const int* __restrict__ cnt, float* __restrict__ dinv, int N) {
    int i = blockIdx.x * 256 + threadIdx.x;
    if (i < N) dinv[i] = rsqrtf((float)(cnt[i] + 1));   // +1 = self loop; deg >= 1 always
}

// single-block exclusive scan over cnt[N] -> offs[N+1]
__global__ __launch_bounds__(1024) void scan_kernel(const int* __restrict__ cnt, int* __restrict__ offs, int N) {
    __shared__ int part[1024];
    int tid = threadIdx.x;
    int chunk = (N + 1023) / 1024;
    int beg = tid * chunk;
    int end = beg + chunk; if (end > N) end = N;
    int s = 0;
    for (int i = beg; i < end; ++i) s += cnt[i];
    part[tid] = s;
    __syncthreads();
    for (int off = 1; off < 1024; off <<= 1) {
        int t = (tid >= off) ? part[tid - off] : 0;
        __syncthreads();
        part[tid] += t;
        __syncthreads();
    }
    int run = (tid > 0) ? part[tid - 1] : 0;
    for (int i = beg; i < end; ++i) { offs[i] = run; run += cnt[i]; }
    if (beg < N && end == N) offs[N] = run;
}

__global__ __launch_bounds__(256) void scatter_kernel(const int* __restrict__ src, const int* __restrict__ dst,
                                                      const int* __restrict__ offs, int* __restrict__ cursor,
                                                      int* __restrict__ csr, int E) {
    for (int e = blockIdx.x * blockDim.x + threadIdx.x; e < E; e += gridDim.x * blockDim.x) {
        int d = dst[e];
        int p = atomicAdd(&cursor[d], 1);
        csr[offs[d] + p] = src[e];
    }
}

// ---------------- weight prep: Wcat[512][128], bcat[128], W3s[32][40], b3s[40] ----------------

__global__ __launch_bounds__(256) void prep_kernel(const float* __restrict__ W1a, const float* __restrict__ W1b,
                                                   const float* __restrict__ W2a, const float* __restrict__ W2b,
                                                   const float* __restrict__ b1a, const float* __restrict__ b1b,
                                                   const float* __restrict__ b2a, const float* __restrict__ b2b,
                                                   const float* __restrict__ W3a, const float* __restrict__ W3b,
                                                   const float* __restrict__ b3a, const float* __restrict__ b3b,
                                                   float* __restrict__ Wcat, float* __restrict__ bcat,
                                                   float* __restrict__ W3s, float* __restrict__ b3s) {
    int idx = blockIdx.x * 256 + threadIdx.x;
    if (idx < 512 * 128) {
        int k = idx >> 7, c = idx & 127;
        const float* W = (c < 32) ? W1a : (c < 64) ? W1b : (c < 96) ? W2a : W2b;
        Wcat[idx] = W[k * 32 + (c & 31)];
    }
    if (idx < 1280) W3s[idx] = W3a[idx] + W3b[idx];
    if (idx < 128) {
        const float* b = (idx < 32) ? b1a : (idx < 64) ? b1b : (idx < 96) ? b2a : b2b;
        bcat[idx] = b[idx & 31];
    }
    if (idx < 40) b3s[idx] = b3a[idx] + b3b[idx];
}

// ---------------- GEMM: HW[N,128] = X[N,512] @ Wcat[512,128] (no bias) ----------------

#define BM 64
#define BK 32

__global__ __launch_bounds__(256) void gemm_x(const float* __restrict__ X, const float* __restrict__ W,
                                              float* __restrict__ HW, int N) {
    __shared__ float xT[BK][BM + 4];   // row stride 68 floats = 272 B (16B aligned)
    __shared__ float wT[BK][128];
    int tid = threadIdx.x;
    int block_row = blockIdx.x * BM;
    int tcol = tid & 31;   // 32 groups x 4 cols
    int trow = tid >> 5;   // 8 groups x 8 rows
    float acc[8][4] = {};

    for (int k0 = 0; k0 < 512; k0 += BK) {
        #pragma unroll
        for (int l = 0; l < 2; ++l) {
            int idx = tid + l * 256;     // 0..511 -> 64 rows x 8 float4
            int r = idx >> 3;
            int kq = idx & 7;
            int gr = block_row + r;
            int grc = gr < N ? gr : N - 1;
            float4 v = *(const float4*)(X + (size_t)grc * 512 + k0 + kq * 4);
            xT[kq * 4 + 0][r] = v.x; xT[kq * 4 + 1][r] = v.y;
            xT[kq * 4 + 2][r] = v.z; xT[kq * 4 + 3][r] = v.w;
        }
        #pragma unroll
        for (int l = 0; l < 4; ++l) {
            int idx = tid + l * 256;     // 0..1023 -> 32 k x 32 float4
            int kk = idx >> 5;
            int cq = idx & 31;
            *(float4*)(&wT[kk][cq * 4]) = *(const float4*)(W + (size_t)(k0 + kk) * 128 + cq * 4);
        }
        __syncthreads();
        #pragma unroll
        for (int kk = 0; kk < BK; ++kk) {
            float4 xa = *(const float4*)(&xT[kk][trow * 8]);
            float4 xb = *(const float4*)(&xT[kk][trow * 8 + 4]);
            float4 wv = *(const float4*)(&wT[kk][tcol * 4]);
            float xr[8] = {xa.x, xa.y, xa.z, xa.w, xb.x, xb.y, xb.z, xb.w};
            float wc[4] = {wv.x, wv.y, wv.z, wv.w};
            #pragma unroll
            for (int r = 0; r < 8; ++r)
                #pragma unroll
                for (int c = 0; c < 4; ++c)
                    acc[r][c] += xr[r] * wc[c];
        }
        __syncthreads();
    }
    #pragma unroll
    for (int r = 0; r < 8; ++r) {
        int gr = block_row + trow * 8 + r;
        if (gr < N) {
            float4 v = make_float4(acc[r][0], acc[r][1], acc[r][2], acc[r][3]);
            *(float4*)(HW + (size_t)gr * 128 + tcol * 4) = v;
        }
    }
}

// ---------------- aggregation (CSR, no atomics) ----------------

// 128 features: 32 lanes/node, float4 each
__global__ __launch_bounds__(256) void agg_kernel128(const float* __restrict__ HW, const float* __restrict__ dinv,
                                                     const int* __restrict__ offs, const int* __restrict__ csr,
                                                     float* __restrict__ AGG, int N) {
    int t = blockIdx.x * 256 + threadIdx.x;
    int node = t >> 5, c = t & 31;
    if (node >= N) return;
    const float4* H4 = (const float4*)HW;
    float di = dinv[node];
    float4 acc = H4[(size_t)node * 32 + c];
    float w0 = di * di;
    acc.x *= w0; acc.y *= w0; acc.z *= w0; acc.w *= w0;
    int e1 = offs[node + 1];
    for (int j = offs[node]; j < e1; ++j) {
        int s = csr[j];
        float w = di * dinv[s];
        float4 h = H4[(size_t)s * 32 + c];
        acc.x += h.x * w; acc.y += h.y * w; acc.z += h.z * w; acc.w += h.w * w;
    }
    ((float4*)AGG)[(size_t)node * 32 + c] = acc;
}

// xs[i][c] = sum_blk relu(AGG[i][32*blk+c] + bcat[32*blk+c])
__global__ __launch_bounds__(256) void xs_kernel(const float* __restrict__ AGG, const float* __restrict__ bcat,
                                                 float* __restrict__ xs, int N) {
    int t = blockIdx.x * 256 + threadIdx.x;
    if (t >= N * 32) return;
    int node = t >> 5, c = t & 31;
    const float* a = AGG + (size_t)node * 128;
    float v = fmaxf(a[c]      + bcat[c],      0.f)
            + fmaxf(a[32 + c] + bcat[32 + c], 0.f)
            + fmaxf(a[64 + c] + bcat[64 + c], 0.f)
            + fmaxf(a[96 + c] + bcat[96 + c], 0.f);
    xs[t] = v;
}

// 32 features: 8 lanes/node, float4 each
__global__ __launch_bounds__(256) void agg_kernel32(const float* __restrict__ xs, const float* __restrict__ dinv,
                                                    const int* __restrict__ offs, const int* __restrict__ csr,
                                                    float* __restrict__ axs, int N) {
    int t = blockIdx.x * 256 + threadIdx.x;
    int node = t >> 3, c = t & 7;
    if (node >= N) return;
    const float4* X4 = (const float4*)xs;
    float di = dinv[node];
    float4 acc = X4[(size_t)node * 8 + c];
    float w0 = di * di;
    acc.x *= w0; acc.y *= w0; acc.z *= w0; acc.w *= w0;
    int e1 = offs[node + 1];
    for (int j = offs[node]; j < e1; ++j) {
        int s = csr[j];
        float w = di * dinv[s];
        float4 h = X4[(size_t)s * 8 + c];
        acc.x += h.x * w; acc.y += h.y * w; acc.z += h.z * w; acc.w += h.w * w;
    }
    ((float4*)axs)[(size_t)node * 8 + c] = acc;
}

// ---------------- final: logits = axs @ W3s + b3s ; log_softmax ----------------

__global__ __launch_bounds__(256) void final_kernel(const float* __restrict__ axs, const float* __restrict__ W3s,
                                                    const float* __restrict__ b3s, float* __restrict__ out, int N) {
    __shared__ float w[32 * 40];
    __shared__ float b[40];
    int tid = threadIdx.x;
    for (int i = tid; i < 1280; i += 256) w[i] = W3s[i];
    if (tid < 40) b[tid] = b3s[tid];
    __syncthreads();
    int i = blockIdx.x * 256 + tid;
    if (i >= N) return;
    float a[32];
    #pragma unroll
    for (int q = 0; q < 8; ++q) {
        float4 v = *(const float4*)(axs + (size_t)i * 32 + q * 4);
        a[q * 4] = v.x; a[q * 4 + 1] = v.y; a[q * 4 + 2] = v.z; a[q * 4 + 3] = v.w;
    }
    float acc[40];
    #pragma unroll
    for (int c = 0; c < 40; ++c) acc[c] = b[c];
    #pragma unroll
    for (int k = 0; k < 32; ++k) {
        float av = a[k];
        #pragma unroll
        for (int c = 0; c < 40; ++c) acc[c] += av * w[k * 40 + c];
    }
    float m = acc[0];
    #pragma unroll
    for (int c = 1; c < 40; ++c) m = fmaxf(m, acc[c]);
    float s = 0.f;
    #pragma unroll
    for (int c = 0; c < 40; ++c) s += expf(acc[c] - m);
    float lg = m + logf(s);
    #pragma unroll
    for (int c = 0; c < 40; ++c) out[(size_t)i * 40 + c] = acc[c] - lg;
}

// ---------------- launch ----------------

extern "C" void kernel_launch(void* const* d_in, const int* in_sizes, int n_in,
                              void* d_out, int out_size, void* d_ws, size_t ws_size,
                              hipStream_t stream) {
    const float* x   = (const float*)d_in[0];
    const int*   ei  = (const int*)d_in[1];
    const float* W1a = (const float*)d_in[2];  const float* b1a = (const float*)d_in[3];
    const float* W1b = (const float*)d_in[4];  const float* b1b = (const float*)d_in[5];
    const float* W2a = (const float*)d_in[6];  const float* b2a = (const float*)d_in[7];
    const float* W2b = (const float*)d_in[8];  const float* b2b = (const float*)d_in[9];
    const float* W3a = (const float*)d_in[10]; const float* b3a = (const float*)d_in[11];
    const float* W3b = (const float*)d_in[12]; const float* b3b = (const float*)d_in[13];

    int N = in_sizes[0] / 512;
    int E = in_sizes[1] / 2;
    const int* srcv = ei;
    const int* dstv = ei + E;

    char* ws = (char*)d_ws;
    size_t off = 0;
    auto alloc = [&](size_t bytes) { void* p = ws + off; off = (off + bytes + 255) & ~(size_t)255; return p; };
    int*   cnt    = (int*)  alloc((size_t)N * 4);
    int*   cursor = (int*)  alloc((size_t)N * 4);
    int*   offs   = (int*)  alloc((size_t)(N + 1) * 4);
    float* dinv   = (float*)alloc((size_t)N * 4);
    int*   csr    = (int*)  alloc((size_t)E * 4);
    float* Wcat   = (float*)alloc(512 * 128 * 4);
    float* bcat   = (float*)alloc(128 * 4);
    float* W3s    = (float*)alloc(1280 * 4);
    float* b3s    = (float*)alloc(40 * 4);
    float* HW     = (float*)alloc((size_t)N * 128 * 4);
    float* AGG    = (float*)alloc((size_t)N * 128 * 4);
    float* xs     = (float*)alloc((size_t)N * 32 * 4);
    float* axs    = HW;   // HW dead after agg_kernel128 -> reuse

    hipMemsetAsync(cnt, 0, (size_t)N * 4, stream);
    hipMemsetAsync(cursor, 0, (size_t)N * 4, stream);

    count_kernel<<<2048, 256, 0, stream>>>(dstv, cnt, E);
    dinv_kernel<<<(N + 255) / 256, 256, 0, stream>>>(cnt, dinv, N);
    scan_kernel<<<1, 1024, 0, stream>>>(cnt, offs, N);
    scatter_kernel<<<2048, 256, 0, stream>>>(srcv, dstv, offs, cursor, csr, E);
    prep_kernel<<<256, 256, 0, stream>>>(W1a, W1b, W2a, W2b, b1a, b1b, b2a, b2b,
                                         W3a, W3b, b3a, b3b, Wcat, bcat, W3s, b3s);
    gemm_x<<<(N + BM - 1) / BM, 256, 0, stream>>>(x, Wcat, HW, N);
    agg_kernel128<<<(N * 32 + 255) / 256, 256, 0, stream>>>(HW, dinv, offs, csr, AGG, N);
    xs_kernel<<<(N * 32 + 255) / 256, 256, 0, stream>>>(AGG, bcat, xs, N);
    agg_kernel32<<<(N * 8 + 255) / 256, 256, 0, stream>>>(xs, dinv, offs, csr, axs, N);
    final_kernel<<<(N + 255) / 256, 256, 0, stream>>>(axs, W3s, b3s, (float*)d_out, N);
}

// Round 2
// 823.402 us; speedup vs baseline: 1.1933x; 1.1933x over previous
//
#include <hip/hip_runtime.h>
#include <hip/hip_bf16.h>
#include <math.h>

typedef __attribute__((ext_vector_type(8))) short short8;
typedef __attribute__((ext_vector_type(4))) float f32x4;

__device__ inline ushort f2bf(float f) {
    uint u = __builtin_bit_cast(uint, f);
    u += 0x7fffu + ((u >> 16) & 1u);          // round-to-nearest-even
    return (ushort)(u >> 16);
}
__device__ inline float bf2f(ushort h) {
    return __builtin_bit_cast(float, (uint)h << 16);
}

// ---------------- degree / CSR build ----------------

__global__ __launch_bounds__(256) void count_kernel(const int* __restrict__ dst, int* __restrict__ cnt, int E) {
    for (int e = blockIdx.x * blockDim.x + threadIdx.x; e < E; e += gridDim.x * blockDim.x)
        atomicAdd(&cnt[dst[e]], 1);
}

__global__ __launch_bounds__(256) void dinv_kernel(const int* __restrict__ cnt, float* __restrict__ dinv, int N) {
    int i = blockIdx.x * 256 + threadIdx.x;
    if (i < N) dinv[i] = rsqrtf((float)(cnt[i] + 1));   // +1 self loop; deg >= 1 always
}

__global__ __launch_bounds__(1024) void scan_kernel(const int* __restrict__ cnt, int* __restrict__ offs, int N) {
    __shared__ int part[1024];
    int tid = threadIdx.x;
    int chunk = (N + 1023) / 1024;
    int beg = tid * chunk;
    int end = beg + chunk; if (end > N) end = N;
    int s = 0;
    for (int i = beg; i < end; ++i) s += cnt[i];
    part[tid] = s;
    __syncthreads();
    for (int off = 1; off < 1024; off <<= 1) {
        int t = (tid >= off) ? part[tid - off] : 0;
        __syncthreads();
        part[tid] += t;
        __syncthreads();
    }
    int run = (tid > 0) ? part[tid - 1] : 0;
    for (int i = beg; i < end; ++i) { offs[i] = run; run += cnt[i]; }
    if (beg < N && end == N) offs[N] = run;
}

__global__ __launch_bounds__(256) void scatter_kernel(const int* __restrict__ src, const int* __restrict__ dst,
                                                      const int* __restrict__ offs, int* __restrict__ cursor,
                                                      int* __restrict__ csr, int E) {
    for (int e = blockIdx.x * blockDim.x + threadIdx.x; e < E; e += gridDim.x * blockDim.x) {
        int d = dst[e];
        int p = atomicAdd(&cursor[d], 1);
        csr[offs[d] + p] = src[e];
    }
}

// ---------------- weight prep: Wt[128][512] bf16 (transposed), bcat[128], W3s[32*40], b3s[40] ----

__global__ __launch_bounds__(256) void prep_kernel(const float* __restrict__ W1a, const float* __restrict__ W1b,
                                                   const float* __restrict__ W2a, const float* __restrict__ W2b,
                                                   const float* __restrict__ b1a, const float* __restrict__ b1b,
                                                   const float* __restrict__ b2a, const float* __restrict__ b2b,
                                                   const float* __restrict__ W3a, const float* __restrict__ W3b,
                                                   const float* __restrict__ b3a, const float* __restrict__ b3b,
                                                   ushort* __restrict__ Wt, float* __restrict__ bcat,
                                                   float* __restrict__ W3s, float* __restrict__ b3s) {
    int idx = blockIdx.x * 256 + threadIdx.x;
    if (idx < 128 * 512) {
        int c = idx >> 9, k = idx & 511;   // Wt[c][k] = Wcat[k][c]
        const float* W = (c < 32) ? W1a : (c < 64) ? W1b : (c < 96) ? W2a : W2b;
        Wt[idx] = f2bf(W[k * 32 + (c & 31)]);
    }
    if (idx < 1280) W3s[idx] = W3a[idx] + W3b[idx];
    if (idx < 128) {
        const float* b = (idx < 32) ? b1a : (idx < 64) ? b1b : (idx < 96) ? b2a : b2b;
        bcat[idx] = b[idx & 31];
    }
    if (idx < 40) b3s[idx] = b3a[idx] + b3b[idx];
}

// ---------------- MFMA GEMM: HWp[N][128] = bf16( (X[N,512] @ Wcat) * dinv[row] ) ----------------
// Block: 256 rows x 128 cols, 4 waves (64 rows each), K-step 64, B double-buffered in LDS.

#define GBM 256

__global__ __launch_bounds__(256) void gemm_mfma(const float* __restrict__ X,
                                                 const ushort* __restrict__ Wt,
                                                 const float* __restrict__ dinv,
                                                 ushort* __restrict__ HWp, int N) {
    __shared__ ushort Blds[2][128 * 64];   // [buf][row][64 k], 16B chunks XOR-swizzled: c' = c ^ (row&7)
    const int tid = threadIdx.x;
    const int lane = tid & 63;
    const int wave = tid >> 6;
    const int rQ = lane & 15, g = lane >> 4;
    const int rowBase = blockIdx.x * GBM + wave * 64;

    // B staging mapping: thread covers weight-row tr, 32-k half th (32B x 2 = 4 chunks)
    const int tr = tid >> 1, th = tid & 1;
    const ushort* wrow = Wt + (size_t)tr * 512 + th * 32;

    f32x4 acc[4][8] = {};

    const float* aptr[4];
    #pragma unroll
    for (int rt = 0; rt < 4; ++rt) {
        int r = rowBase + rt * 16 + rQ;
        if (r > N - 1) r = N - 1;
        aptr[rt] = X + (size_t)r * 512 + g * 8;
    }

    uint4 bregA[4], bregB[4];
    float4 araw[4][4];   // [rowTile][sub*2 + half]

    #pragma unroll
    for (int i = 0; i < 4; ++i) bregA[i] = *(const uint4*)(wrow + i * 8);

#define STAGE_B(buf, breg)                                                 \
    {                                                                      \
        ushort* bp = &Blds[buf][tr * 64];                                  \
        _Pragma("unroll")                                                  \
        for (int i = 0; i < 4; ++i) {                                      \
            int c = th * 4 + i;                                            \
            int cp = c ^ (tr & 7);                                         \
            *(uint4*)(bp + cp * 8) = breg[i];                              \
        }                                                                  \
    }

#define LOAD_B(breg, k0)                                                   \
    {                                                                      \
        _Pragma("unroll")                                                  \
        for (int i = 0; i < 4; ++i) breg[i] = *(const uint4*)(wrow + (k0) + i * 8); \
    }

#define LOAD_A(k0)                                                         \
    {                                                                      \
        _Pragma("unroll")                                                  \
        for (int rt = 0; rt < 4; ++rt) {                                   \
            araw[rt][0] = *(const float4*)(aptr[rt] + (k0));               \
            araw[rt][1] = *(const float4*)(aptr[rt] + (k0) + 4);           \
            araw[rt][2] = *(const float4*)(aptr[rt] + (k0) + 32);          \
            araw[rt][3] = *(const float4*)(aptr[rt] + (k0) + 36);          \
        }                                                                  \
    }

#define COMPUTE(buf)                                                       \
    {                                                                      \
        short8 afrag[4][2];                                                \
        _Pragma("unroll")                                                  \
        for (int rt = 0; rt < 4; ++rt) {                                   \
            _Pragma("unroll")                                              \
            for (int sub = 0; sub < 2; ++sub) {                            \
                union { short8 s8; __hip_bfloat162 h[4]; } u;              \
                float4 lo = araw[rt][sub * 2], hi = araw[rt][sub * 2 + 1]; \
                u.h[0] = __float22bfloat162_rn({lo.x, lo.y});              \
                u.h[1] = __float22bfloat162_rn({lo.z, lo.w});              \
                u.h[2] = __float22bfloat162_rn({hi.x, hi.y});              \
                u.h[3] = __float22bfloat162_rn({hi.z, hi.w});              \
                afrag[rt][sub] = u.s8;                                     \
            }                                                              \
        }                                                                  \
        const ushort* bbase = &Blds[buf][0];                               \
        _Pragma("unroll")                                                  \
        for (int ct = 0; ct < 8; ++ct) {                                   \
            int brow = ct * 16 + rQ;                                       \
            _Pragma("unroll")                                              \
            for (int sub = 0; sub < 2; ++sub) {                            \
                int c = sub * 4 + g;                                       \
                int cp = c ^ (brow & 7);                                   \
                short8 bfrag = *(const short8*)(bbase + brow * 64 + cp * 8); \
                _Pragma("unroll")                                          \
                for (int rt = 0; rt < 4; ++rt)                             \
                    acc[rt][ct] = __builtin_amdgcn_mfma_f32_16x16x32_bf16( \
                        afrag[rt][sub], bfrag, acc[rt][ct], 0, 0, 0);      \
            }                                                              \
        }                                                                  \
    }

    for (int s = 0; s < 8; s += 2) {
        STAGE_B(0, bregA);
        LOAD_A(s * 64);
        if (s + 1 < 8) LOAD_B(bregB, (s + 1) * 64);
        __syncthreads();
        COMPUTE(0);
        STAGE_B(1, bregB);
        LOAD_A((s + 1) * 64);
        if (s + 2 < 8) LOAD_B(bregA, (s + 2) * 64);
        __syncthreads();
        COMPUTE(1);
    }

    // epilogue: scale by dinv[row], store bf16
    #pragma unroll
    for (int rt = 0; rt < 4; ++rt) {
        float dv[4]; int rw[4];
        #pragma unroll
        for (int j = 0; j < 4; ++j) {
            int r = rowBase + rt * 16 + g * 4 + j;
            rw[j] = r;
            dv[j] = (r < N) ? dinv[r] : 0.f;
        }
        #pragma unroll
        for (int ct = 0; ct < 8; ++ct)
            #pragma unroll
            for (int j = 0; j < 4; ++j)
                if (rw[j] < N)
                    HWp[(size_t)rw[j] * 128 + ct * 16 + rQ] = f2bf(acc[rt][ct][j] * dv[j]);
    }
#undef STAGE_B
#undef LOAD_B
#undef LOAD_A
#undef COMPUTE
}

// ---------------- aggregation 128 (bf16 gather) + fused relu/bias/block-sum -> xsp ----------------
// HWp pre-scaled by dinv[src]. xsp[node] = dinv[node] * sum_blk relu(dinv[node]*agg + bcat)

__global__ __launch_bounds__(256) void agg128(const ushort* __restrict__ HWp, const float* __restrict__ dinv,
                                              const int* __restrict__ offs, const int* __restrict__ csr,
                                              const float* __restrict__ bcat, float* __restrict__ xsp, int N) {
    int t = blockIdx.x * 256 + threadIdx.x;
    int node = t >> 5, c = t & 31;      // lane c holds features 4c..4c+3
    if (node >= N) return;
    const ushort4* H = (const ushort4*)HWp;
    ushort4 h = H[(size_t)node * 32 + c];
    float ax = bf2f(h.x), ay = bf2f(h.y), az = bf2f(h.z), aw = bf2f(h.w);
    int e1 = offs[node + 1];
    for (int j = offs[node]; j < e1; ++j) {
        int s = csr[j];
        ushort4 v = H[(size_t)s * 32 + c];
        ax += bf2f(v.x); ay += bf2f(v.y); az += bf2f(v.z); aw += bf2f(v.w);
    }
    float di = dinv[node];
    float4 b = *(const float4*)(bcat + c * 4);
    float rx = fmaxf(di * ax + b.x, 0.f);
    float ry = fmaxf(di * ay + b.y, 0.f);
    float rz = fmaxf(di * az + b.z, 0.f);
    float rw = fmaxf(di * aw + b.w, 0.f);
    rx += __shfl_xor(rx, 8);  ry += __shfl_xor(ry, 8);  rz += __shfl_xor(rz, 8);  rw += __shfl_xor(rw, 8);
    rx += __shfl_xor(rx, 16); ry += __shfl_xor(ry, 16); rz += __shfl_xor(rz, 16); rw += __shfl_xor(rw, 16);
    if ((c & 24) == 0) {   // lanes c=0..7 hold block-sums for features 4c..4c+3
        float4 o = make_float4(rx * di, ry * di, rz * di, rw * di);
        *(float4*)(xsp + (size_t)node * 32 + c * 4) = o;
    }
}

// ---------------- aggregation 32 (xsp pre-scaled) -> axs ----------------

__global__ __launch_bounds__(256) void agg32(const float* __restrict__ xsp, const float* __restrict__ dinv,
                                             const int* __restrict__ offs, const int* __restrict__ csr,
                                             float* __restrict__ axs, int N) {
    int t = blockIdx.x * 256 + threadIdx.x;
    int node = t >> 3, c = t & 7;
    if (node >= N) return;
    const float4* X4 = (const float4*)xsp;
    float4 acc = X4[(size_t)node * 8 + c];
    int e1 = offs[node + 1];
    for (int j = offs[node]; j < e1; ++j) {
        int s = csr[j];
        float4 v = X4[(size_t)s * 8 + c];
        acc.x += v.x; acc.y += v.y; acc.z += v.z; acc.w += v.w;
    }
    float di = dinv[node];
    acc.x *= di; acc.y *= di; acc.z *= di; acc.w *= di;
    ((float4*)axs)[(size_t)node * 8 + c] = acc;
}

// ---------------- final: logits = axs @ W3s + b3s ; log_softmax ----------------

__global__ __launch_bounds__(256) void final_kernel(const float* __restrict__ axs, const float* __restrict__ W3s,
                                                    const float* __restrict__ b3s, float* __restrict__ out, int N) {
    __shared__ float w[32 * 40];
    __shared__ float b[40];
    int tid = threadIdx.x;
    for (int i = tid; i < 1280; i += 256) w[i] = W3s[i];
    if (tid < 40) b[tid] = b3s[tid];
    __syncthreads();
    int i = blockIdx.x * 256 + tid;
    if (i >= N) return;
    float a[32];
    #pragma unroll
    for (int q = 0; q < 8; ++q) {
        float4 v = *(const float4*)(axs + (size_t)i * 32 + q * 4);
        a[q * 4] = v.x; a[q * 4 + 1] = v.y; a[q * 4 + 2] = v.z; a[q * 4 + 3] = v.w;
    }
    float acc[40];
    #pragma unroll
    for (int c = 0; c < 40; ++c) acc[c] = b[c];
    #pragma unroll
    for (int k = 0; k < 32; ++k) {
        float av = a[k];
        #pragma unroll
        for (int c = 0; c < 40; ++c) acc[c] += av * w[k * 40 + c];
    }
    float m = acc[0];
    #pragma unroll
    for (int c = 1; c < 40; ++c) m = fmaxf(m, acc[c]);
    float s = 0.f;
    #pragma unroll
    for (int c = 0; c < 40; ++c) s += expf(acc[c] - m);
    float lg = m + logf(s);
    #pragma unroll
    for (int c = 0; c < 40; ++c) out[(size_t)i * 40 + c] = acc[c] - lg;
}

// ---------------- launch ----------------

extern "C" void kernel_launch(void* const* d_in, const int* in_sizes, int n_in,
                              void* d_out, int out_size, void* d_ws, size_t ws_size,
                              hipStream_t stream) {
    const float* x   = (const float*)d_in[0];
    const int*   ei  = (const int*)d_in[1];
    const float* W1a = (const float*)d_in[2];  const float* b1a = (const float*)d_in[3];
    const float* W1b = (const float*)d_in[4];  const float* b1b = (const float*)d_in[5];
    const float* W2a = (const float*)d_in[6];  const float* b2a = (const float*)d_in[7];
    const float* W2b = (const float*)d_in[8];  const float* b2b = (const float*)d_in[9];
    const float* W3a = (const float*)d_in[10]; const float* b3a = (const float*)d_in[11];
    const float* W3b = (const float*)d_in[12]; const float* b3b = (const float*)d_in[13];

    int N = in_sizes[0] / 512;
    int E = in_sizes[1] / 2;
    const int* srcv = ei;
    const int* dstv = ei + E;

    char* ws = (char*)d_ws;
    size_t off = 0;
    auto alloc = [&](size_t bytes) { void* p = ws + off; off = (off + bytes + 255) & ~(size_t)255; return p; };
    int*    cnt    = (int*)   alloc((size_t)N * 4);
    int*    cursor = (int*)   alloc((size_t)N * 4);
    int*    offs   = (int*)   alloc((size_t)(N + 1) * 4);
    float*  dinv   = (float*) alloc((size_t)N * 4);
    int*    csr    = (int*)   alloc((size_t)E * 4);
    ushort* Wt     = (ushort*)alloc(128 * 512 * 2);
    float*  bcat   = (float*) alloc(128 * 4);
    float*  W3s    = (float*) alloc(1280 * 4);
    float*  b3s    = (float*) alloc(40 * 4);
    ushort* HWp    = (ushort*)alloc((size_t)N * 128 * 2);
    float*  xsp    = (float*) alloc((size_t)N * 32 * 4);
    float*  axs    = (float*) alloc((size_t)N * 32 * 4);

    hipMemsetAsync(cnt, 0, (size_t)N * 4, stream);
    hipMemsetAsync(cursor, 0, (size_t)N * 4, stream);

    count_kernel<<<2048, 256, 0, stream>>>(dstv, cnt, E);
    dinv_kernel<<<(N + 255) / 256, 256, 0, stream>>>(cnt, dinv, N);
    scan_kernel<<<1, 1024, 0, stream>>>(cnt, offs, N);
    scatter_kernel<<<2048, 256, 0, stream>>>(srcv, dstv, offs, cursor, csr, E);
    prep_kernel<<<256, 256, 0, stream>>>(W1a, W1b, W2a, W2b, b1a, b1b, b2a, b2b,
                                         W3a, W3b, b3a, b3b, Wt, bcat, W3s, b3s);
    gemm_mfma<<<(N + GBM - 1) / GBM, 256, 0, stream>>>(x, Wt, dinv, HWp, N);
    agg128<<<((size_t)N * 32 + 255) / 256, 256, 0, stream>>>(HWp, dinv, offs, csr, bcat, xsp, N);
    agg32<<<((size_t)N * 8 + 255) / 256, 256, 0, stream>>>(xsp, dinv, offs, csr, axs, N);
    final_kernel<<<(N + 255) / 256, 256, 0, stream>>>(axs, W3s, b3s, (float*)d_out, N);
}